// Round 7
// baseline (282.760 us; speedup 1.0000x reference)
//
#include <hip/hip_runtime.h>

#define NPG 127
#define EPG 2032
#define NGRAPH 4096
#define NE (EPG * NGRAPH)

// per-wave LDS region (float offsets); total 3812 floats = 15248 B
#define WREG 3812
#define R_CSR    0      // u8[2032]  -> 508 floats
#define R_STARTS 508    // u32[128]  (counts -> exclusive CSR starts, in place)
#define R_CURSOR 636    // u32[128]
#define R_XS     764    // f32[508]  : 127 rows x 4 (dinv-scaled x, slot3 pad)
#define R_HS2    1272   // f32[2540] : 127 rows x 20 (dinv-scaled h1, 4f pad)
#define R_H2     0      // f32[3556] : overlays everything after agg2 is done

// wave-phase fence: drain LDS ops + compiler ordering barrier (DS pipe is
// in-order per wave, so this is cheap belt-and-suspenders)
#define WFENCE() asm volatile("s_waitcnt lgkmcnt(0)" ::: "memory")

__device__ __forceinline__ void agg1_node(float* A, const unsigned* st,
        const unsigned char* csr8, int i, float di,
        float sx, float sy, float sz, const float* w1s, const float* b1s)
{
    float ax = sx, ay = sy, az = sz;            // self-loop term (pre-scaled)
    const unsigned e0 = st[i], e1 = st[i + 1];
    for (unsigned k = e0; k < e1; ++k) {
        const int s = csr8[k];
        const float4 v = *(const float4*)(A + R_XS + s * 4);
        ax += v.x; ay += v.y; az += v.z;
    }
    ax *= di; ay *= di; az *= di;
    float* hrow = A + R_HS2 + i * 20;
    #pragma unroll
    for (int f4 = 0; f4 < 4; ++f4) {
        const float4 wa = *(const float4*)(w1s + f4 * 4);
        const float4 wb = *(const float4*)(w1s + 16 + f4 * 4);
        const float4 wc = *(const float4*)(w1s + 32 + f4 * 4);
        const float4 bb = *(const float4*)(b1s + f4 * 4);
        float4 h;
        h.x = fmaxf(fmaf(ax, wa.x, fmaf(ay, wb.x, fmaf(az, wc.x, bb.x))), 0.f) * di;
        h.y = fmaxf(fmaf(ax, wa.y, fmaf(ay, wb.y, fmaf(az, wc.y, bb.y))), 0.f) * di;
        h.z = fmaxf(fmaf(ax, wa.z, fmaf(ay, wb.z, fmaf(az, wc.z, bb.z))), 0.f) * di;
        h.w = fmaxf(fmaf(ax, wa.w, fmaf(ay, wb.w, fmaf(az, wc.w, bb.w))), 0.f) * di;
        *(float4*)(hrow + f4 * 4) = h;
    }
}

__device__ __forceinline__ void agg2_node(const float* A, const unsigned* st,
        const unsigned char* csr8, int i, float di,
        float4& c0, float4& c1, float4& c2, float4& c3)
{
    const float* base = A + R_HS2;
    const float* r = base + i * 20;             // self-loop term
    c0 = *(const float4*)(r);
    c1 = *(const float4*)(r + 4);
    c2 = *(const float4*)(r + 8);
    c3 = *(const float4*)(r + 12);
    const unsigned e0 = st[i], e1 = st[i + 1];
    for (unsigned k = e0; k < e1; ++k) {
        const int s = csr8[k];
        const float* p = base + s * 20;         // stride 20f: banks uniform
        const float4 v0 = *(const float4*)(p);
        const float4 v1 = *(const float4*)(p + 4);
        const float4 v2 = *(const float4*)(p + 8);
        const float4 v3 = *(const float4*)(p + 12);
        c0.x += v0.x; c0.y += v0.y; c0.z += v0.z; c0.w += v0.w;
        c1.x += v1.x; c1.y += v1.y; c1.z += v1.z; c1.w += v1.w;
        c2.x += v2.x; c2.y += v2.y; c2.z += v2.z; c2.w += v2.w;
        c3.x += v3.x; c3.y += v3.y; c3.z += v3.z; c3.w += v3.w;
    }
    c0.x *= di; c0.y *= di; c0.z *= di; c0.w *= di;
    c1.x *= di; c1.y *= di; c1.z *= di; c1.w *= di;
    c2.x *= di; c2.y *= di; c2.z *= di; c2.w *= di;
    c3.x *= di; c3.y *= di; c3.z *= di; c3.w *= di;
}

__device__ __forceinline__ void transform_node(float* A, int i,
        float4 c0, float4 c1, float4 c2, float4 c3,
        const float* w2s, const float* b2s)
{
    float acc[28];
    #pragma unroll
    for (int f4 = 0; f4 < 7; ++f4) {
        const float4 b = *(const float4*)(b2s + f4 * 4);
        acc[f4 * 4 + 0] = b.x; acc[f4 * 4 + 1] = b.y;
        acc[f4 * 4 + 2] = b.z; acc[f4 * 4 + 3] = b.w;
    }
    const float a2arr[16] = {c0.x, c0.y, c0.z, c0.w, c1.x, c1.y, c1.z, c1.w,
                             c2.x, c2.y, c2.z, c2.w, c3.x, c3.y, c3.z, c3.w};
    #pragma unroll
    for (int k = 0; k < 16; ++k) {
        const float a = a2arr[k];
        #pragma unroll
        for (int f4 = 0; f4 < 7; ++f4) {
            const float4 wv = *(const float4*)(w2s + k * 28 + f4 * 4);   // broadcast
            acc[f4 * 4 + 0] = fmaf(a, wv.x, acc[f4 * 4 + 0]);
            acc[f4 * 4 + 1] = fmaf(a, wv.y, acc[f4 * 4 + 1]);
            acc[f4 * 4 + 2] = fmaf(a, wv.z, acc[f4 * 4 + 2]);
            acc[f4 * 4 + 3] = fmaf(a, wv.w, acc[f4 * 4 + 3]);
        }
    }
    float* hrow = A + R_H2 + i * 28;
    #pragma unroll
    for (int f4 = 0; f4 < 7; ++f4) {
        float4 h;
        h.x = fmaxf(acc[f4 * 4 + 0], 0.f);
        h.y = fmaxf(acc[f4 * 4 + 1], 0.f);
        h.z = fmaxf(acc[f4 * 4 + 2], 0.f);
        h.w = fmaxf(acc[f4 * 4 + 3], 0.f);
        *(float4*)(hrow + f4 * 4) = h;
    }
}

__global__ __launch_bounds__(256, 2) void gcn_fused(
    const float* __restrict__ x, const int* __restrict__ ei,
    const float* __restrict__ W1, const float* __restrict__ b1,
    const float* __restrict__ W2, const float* __restrict__ b2,
    const float* __restrict__ lw1, const float* __restrict__ lb1,
    const float* __restrict__ lw2, const float* __restrict__ lb2,
    float* __restrict__ out)
{
    __shared__ __align__(16) float arena[4 * WREG];     // 60992 B
    __shared__ __align__(16) float w1s[48], b1s[16], w2s[448], b2s[28];
    __shared__ __align__(16) float lb1s[16], lw2s[32], lb2s[2];

    const int t = threadIdx.x;
    const int lane = t & 63;
    const int w = t >> 6;
    const int gi = blockIdx.x * 4 + w;                  // one graph per wave
    float* A = arena + w * WREG;
    unsigned* cnt = (unsigned*)(A + R_STARTS);          // counts -> starts
    unsigned* cur = (unsigned*)(A + R_CURSOR);
    unsigned char* csr8 = (unsigned char*)(A + R_CSR);
    const int nodebase = gi * NPG;
    const long ebase = (long)gi * EPG;

    // ---- weights (block-cooperative, the ONLY barrier) ----
    if (t < 48)       w1s[t]        = W1[t];
    else if (t < 64)  b1s[t - 48]   = b1[t - 48];
    else if (t < 92)  b2s[t - 64]   = b2[t - 64];
    else if (t < 108) lb1s[t - 92]  = lb1[t - 92];
    else if (t < 140) lw2s[t - 108] = lw2[t - 108];
    else if (t < 142) lb2s[t - 140] = lb2[t - 140];
    for (int i = t; i < 448; i += 256) w2s[i] = W2[i];

    // ---- dtype probe (per wave): int64 has all-zero hi-words ----
    const int hiw = ei[2 * lane + 1];
    const bool is64 = (__ballot(hiw != 0) == 0ULL);

    // ---- zero degree counts ----
    cnt[lane] = 0u;
    cnt[lane + 64] = 0u;
    WFENCE();
    __syncthreads();

    // ---- count in-degrees (edges read straight from global) ----
    if (is64) {
        const long long* ei64 = (const long long*)ei;
        const longlong2* d2 = (const longlong2*)(ei64 + NE + ebase);
        for (int q = lane; q < EPG / 2; q += 64) {
            const longlong2 dd = d2[q];
            atomicAdd(&cnt[(int)dd.x - nodebase], 1u);
            atomicAdd(&cnt[(int)dd.y - nodebase], 1u);
        }
    } else {
        const int4* d4 = (const int4*)(ei + NE + ebase);
        for (int q = lane; q < EPG / 4; q += 64) {
            const int4 dd = d4[q];
            atomicAdd(&cnt[dd.x - nodebase], 1u);
            atomicAdd(&cnt[dd.y - nodebase], 1u);
            atomicAdd(&cnt[dd.z - nodebase], 1u);
            atomicAdd(&cnt[dd.w - nodebase], 1u);
        }
    }
    WFENCE();

    // ---- degrees for own nodes; wave shfl-scan -> starts/cursor ----
    const int i0 = lane, i1 = lane + 64;
    const bool v1 = (i1 < NPG);
    const unsigned deg0 = cnt[i0];
    const unsigned deg1 = v1 ? cnt[i1] : 0u;
    const unsigned c0 = cnt[2 * lane], c1 = cnt[2 * lane + 1];
    const float d0 = rsqrtf((float)(deg0 + 1u));
    const float d1 = rsqrtf((float)(deg1 + 1u));
    asm volatile("" ::: "memory");
    unsigned ps = c0 + c1, sc = ps;
    #pragma unroll
    for (int dd = 1; dd < 64; dd <<= 1) {
        const unsigned u = __shfl_up(sc, dd);
        if (lane >= dd) sc += u;
    }
    const unsigned excl = sc - ps;                      // exclusive pair offset
    cnt[2 * lane] = excl;                               // starts, in place
    cnt[2 * lane + 1] = excl + c0;
    cur[2 * lane] = excl;
    cur[2 * lane + 1] = excl + c0;

    // ---- own dinv-scaled x -> registers + xs rows ----
    float sx0, sy0, sz0, sx1 = 0.f, sy1 = 0.f, sz1 = 0.f;
    {
        const float* xp = x + (long)(nodebase + i0) * 3;
        sx0 = xp[0] * d0; sy0 = xp[1] * d0; sz0 = xp[2] * d0;
        const float4 xv = {sx0, sy0, sz0, 0.f};
        *(float4*)(A + R_XS + i0 * 4) = xv;
        if (v1) {
            const float* xq = x + (long)(nodebase + i1) * 3;
            sx1 = xq[0] * d1; sy1 = xq[1] * d1; sz1 = xq[2] * d1;
            const float4 xw = {sx1, sy1, sz1, 0.f};
            *(float4*)(A + R_XS + i1 * 4) = xw;
        }
    }
    WFENCE();

    // ---- scatter edges into u8 CSR (re-read edges, L2-hot) ----
    if (is64) {
        const long long* ei64 = (const long long*)ei;
        const longlong2* s2 = (const longlong2*)(ei64 + ebase);
        const longlong2* d2 = (const longlong2*)(ei64 + NE + ebase);
        for (int q = lane; q < EPG / 2; q += 64) {
            const longlong2 ss = s2[q], dd = d2[q];
            unsigned p0 = atomicAdd(&cur[(int)dd.x - nodebase], 1u);
            csr8[p0] = (unsigned char)((int)ss.x - nodebase);
            unsigned p1 = atomicAdd(&cur[(int)dd.y - nodebase], 1u);
            csr8[p1] = (unsigned char)((int)ss.y - nodebase);
        }
    } else {
        const int4* s4 = (const int4*)(ei + ebase);
        const int4* d4 = (const int4*)(ei + NE + ebase);
        for (int q = lane; q < EPG / 4; q += 64) {
            const int4 ss = s4[q], dd = d4[q];
            unsigned p0 = atomicAdd(&cur[dd.x - nodebase], 1u);
            csr8[p0] = (unsigned char)(ss.x - nodebase);
            unsigned p1 = atomicAdd(&cur[dd.y - nodebase], 1u);
            csr8[p1] = (unsigned char)(ss.y - nodebase);
            unsigned p2 = atomicAdd(&cur[dd.z - nodebase], 1u);
            csr8[p2] = (unsigned char)(ss.z - nodebase);
            unsigned p3 = atomicAdd(&cur[dd.w - nodebase], 1u);
            csr8[p3] = (unsigned char)(ss.w - nodebase);
        }
    }
    WFENCE();

    // ---- layer 1: aggregate x (3f) then transform 3->16, prescale ----
    const unsigned* st = cnt;
    agg1_node(A, st, csr8, i0, d0, sx0, sy0, sz0, w1s, b1s);
    if (v1) agg1_node(A, st, csr8, i1, d1, sx1, sy1, sz1, w1s, b1s);
    WFENCE();

    // ---- layer 2: aggregate h1 (16f) into registers ----
    float4 a0, a1, a2, a3, e0v, e1v, e2v, e3v;
    agg2_node(A, st, csr8, i0, d0, a0, a1, a2, a3);
    if (v1) agg2_node(A, st, csr8, i1, d1, e0v, e1v, e2v, e3v);
    WFENCE();

    // ---- 16->28 transform + relu -> h2 (overlays dead regions) ----
    transform_node(A, i0, a0, a1, a2, a3, w2s, b2s);
    if (v1) transform_node(A, i1, e0v, e1v, e2v, e3v, w2s, b2s);
    WFENCE();

    // ---- head: pj += h2[r] * lw1[r][:], r strided by lane ----
    float pj[16];
    #pragma unroll
    for (int j = 0; j < 16; ++j) pj[j] = 0.f;
    const float4* lw14 = (const float4*)lw1;
    for (int r = lane; r < NPG * 28; r += 64) {
        const float hv = A[R_H2 + r];
        const float4 aa = lw14[(long)r * 4 + 0];
        const float4 bb = lw14[(long)r * 4 + 1];
        const float4 cc = lw14[(long)r * 4 + 2];
        const float4 ddv = lw14[(long)r * 4 + 3];
        pj[0]  = fmaf(hv, aa.x, pj[0]);  pj[1]  = fmaf(hv, aa.y, pj[1]);
        pj[2]  = fmaf(hv, aa.z, pj[2]);  pj[3]  = fmaf(hv, aa.w, pj[3]);
        pj[4]  = fmaf(hv, bb.x, pj[4]);  pj[5]  = fmaf(hv, bb.y, pj[5]);
        pj[6]  = fmaf(hv, bb.z, pj[6]);  pj[7]  = fmaf(hv, bb.w, pj[7]);
        pj[8]  = fmaf(hv, cc.x, pj[8]);  pj[9]  = fmaf(hv, cc.y, pj[9]);
        pj[10] = fmaf(hv, cc.z, pj[10]); pj[11] = fmaf(hv, cc.w, pj[11]);
        pj[12] = fmaf(hv, ddv.x, pj[12]); pj[13] = fmaf(hv, ddv.y, pj[13]);
        pj[14] = fmaf(hv, ddv.z, pj[14]); pj[15] = fmaf(hv, ddv.w, pj[15]);
    }
    // 64-lane butterfly: every lane ends with the full sums
    #pragma unroll
    for (int j = 0; j < 16; ++j) {
        float v = pj[j];
        v += __shfl_xor(v, 1);
        v += __shfl_xor(v, 2);
        v += __shfl_xor(v, 4);
        v += __shfl_xor(v, 8);
        v += __shfl_xor(v, 16);
        v += __shfl_xor(v, 32);
        pj[j] = fmaxf(v + lb1s[j], 0.f);                // g vector
    }
    if (lane < 2) {
        float o = lb2s[lane];
        #pragma unroll
        for (int j = 0; j < 16; ++j) o = fmaf(pj[j], lw2s[j * 2 + lane], o);
        out[gi * 2 + lane] = o;
    }
}

extern "C" void kernel_launch(void* const* d_in, const int* in_sizes, int n_in,
                              void* d_out, int out_size, void* d_ws, size_t ws_size,
                              hipStream_t stream) {
    const float* x   = (const float*)d_in[0];
    const int*   ei  = (const int*)d_in[1];
    const float* W1  = (const float*)d_in[2];
    const float* b1  = (const float*)d_in[3];
    const float* W2  = (const float*)d_in[4];
    const float* b2  = (const float*)d_in[5];
    const float* lw1 = (const float*)d_in[6];
    const float* lb1 = (const float*)d_in[7];
    const float* lw2 = (const float*)d_in[8];
    const float* lb2 = (const float*)d_in[9];
    float* out = (float*)d_out;

    gcn_fused<<<NGRAPH / 4, 256, 0, stream>>>(x, ei, W1, b1, W2, b2,
                                              lw1, lb1, lw2, lb2, out);
}

// Round 8
// 182.135 us; speedup vs baseline: 1.5525x; 1.5525x over previous
//
#include <hip/hip_runtime.h>

#define NPG 127
#define EPG 2032
#define NGRAPH 4096
#define NE (EPG * NGRAPH)
#define F1 16
#define F2 28

// arena overlays (float offsets), all transitions barrier-separated:
// [0,2032)    epk (count/scatter) -> HS2 127x16 rot-swz (agg1 w, agg2 r) -> H2
// [2032,2540) XS 127x4 dinv-scaled x (agg1 r)                            -> H2
// [2540,3048) csr8 u8[2032] (scatter w, agg1/agg2 r)                     -> H2
// [3048,3556) H2 only
#define A_EPK 0
#define A_HS2 0
#define A_XS  2032
#define A_CSR 2540
#define A_H2  0
#define ARENA 3556

__global__ __launch_bounds__(256, 6) void gcn_fused(
    const float* __restrict__ x, const int* __restrict__ ei,
    const float* __restrict__ W1, const float* __restrict__ b1,
    const float* __restrict__ W2, const float* __restrict__ b2,
    const float* __restrict__ lw1, const float* __restrict__ lb1,
    const float* __restrict__ lw2, const float* __restrict__ lb2,
    float* __restrict__ out)
{
    __shared__ __align__(16) float arena[ARENA];        // 14224 B
    __shared__ unsigned cnt[128], starts[128], cursor[128];
    __shared__ float dinv[NPG];
    __shared__ __align__(16) float w1s[48], b1s[F1], w2s[448], b2s[F2];
    __shared__ float lb1s[16], lw2s[32], lb2s[2];
    __shared__ float wsum[64], gsh[16];
    __shared__ int is64;

    const int t = threadIdx.x;
    const int g = blockIdx.x;
    const int nodebase = g * NPG;
    const long ebase = (long)g * EPG;

    // ---- dtype probe (wave 0): int64 edge_index has all-zero hi-words ----
    if (t < 64) {
        const int hiw = ei[2 * t + 1];
        const unsigned long long m = __ballot(hiw != 0);
        if (t == 0) is64 = (m == 0ULL) ? 1 : 0;
    }
    // ---- weights + zero counts ----
    if (t < 48)       w1s[t]        = W1[t];
    else if (t < 64)  b1s[t - 48]   = b1[t - 48];
    else if (t < 92)  b2s[t - 64]   = b2[t - 64];
    else if (t < 108) lb1s[t - 92]  = lb1[t - 92];
    else if (t < 140) lw2s[t - 108] = lw2[t - 108];
    else if (t < 142) lb2s[t - 140] = lb2[t - 140];
    for (int q = t; q < 448; q += 256) w2s[q] = W2[q];
    if (t < 128) cnt[t] = 0u;
    __syncthreads();                                    // B1

    // ---- load edges once (vectorized): pack (src,dst), count in-degree ----
    int* epk = (int*)&arena[A_EPK];
    if (is64) {
        const long long* ei64 = (const long long*)ei;
        const longlong2* s2 = (const longlong2*)(ei64 + ebase);
        const longlong2* d2 = (const longlong2*)(ei64 + NE + ebase);
        for (int q = t; q < EPG / 2; q += 256) {
            const longlong2 ss = s2[q], dd = d2[q];
            const int sa = (int)ss.x - nodebase, da = (int)dd.x - nodebase;
            const int sb = (int)ss.y - nodebase, db = (int)dd.y - nodebase;
            epk[2 * q + 0] = (sa << 8) | da;  atomicAdd(&cnt[da], 1u);
            epk[2 * q + 1] = (sb << 8) | db;  atomicAdd(&cnt[db], 1u);
        }
    } else {
        const int4* s4 = (const int4*)(ei + ebase);
        const int4* d4 = (const int4*)(ei + NE + ebase);
        for (int q = t; q < EPG / 4; q += 256) {
            const int4 ss = s4[q], dd = d4[q];
            const int eb = 4 * q;
            epk[eb + 0] = ((ss.x - nodebase) << 8) | (dd.x - nodebase);
            epk[eb + 1] = ((ss.y - nodebase) << 8) | (dd.y - nodebase);
            epk[eb + 2] = ((ss.z - nodebase) << 8) | (dd.z - nodebase);
            epk[eb + 3] = ((ss.w - nodebase) << 8) | (dd.w - nodebase);
            atomicAdd(&cnt[dd.x - nodebase], 1u);
            atomicAdd(&cnt[dd.y - nodebase], 1u);
            atomicAdd(&cnt[dd.z - nodebase], 1u);
            atomicAdd(&cnt[dd.w - nodebase], 1u);
        }
    }
    __syncthreads();                                    // B2

    // ---- wave-0 pair shfl-scan -> starts/cursor (cnt preserved) ----
    if (t < 64) {
        const unsigned ca = cnt[2 * t], cb = cnt[2 * t + 1];
        const unsigned ps = ca + cb;
        unsigned sc = ps;
        #pragma unroll
        for (int d = 1; d < 64; d <<= 1) {
            const unsigned u = __shfl_up(sc, d);
            if (t >= d) sc += u;
        }
        const unsigned excl = sc - ps;                  // exclusive pair offset
        starts[2 * t] = excl;            cursor[2 * t] = excl;
        starts[2 * t + 1] = excl + ca;   cursor[2 * t + 1] = excl + ca;
    }
    // ---- dinv + dinv-scaled x rows (reads cnt only) ----
    if (t < NPG) {
        const float dv = rsqrtf((float)(cnt[t] + 1u));  // +1 self-loop
        dinv[t] = dv;
        const float* xp = x + (long)(nodebase + t) * 3;
        const float4 xv = {xp[0] * dv, xp[1] * dv, xp[2] * dv, 0.f};
        *(float4*)&arena[A_XS + t * 4] = xv;
    }
    __syncthreads();                                    // B3

    // ---- scatter into u8 CSR ----
    unsigned char* csr8 = (unsigned char*)&arena[A_CSR];
    for (int e = t; e < EPG; e += 256) {
        const int pk = epk[e];
        const int d = pk & 255, s = pk >> 8;
        const unsigned pos = atomicAdd(&cursor[d], 1u);
        csr8[pos] = (unsigned char)s;
    }
    __syncthreads();                                    // B4

    const int i = t >> 1, half = t & 1;                 // 2 threads per node
    const bool act = (t < 2 * NPG);
    float di = 0.f; unsigned e0 = 0, e1 = 0;
    if (act) { di = dinv[i]; e0 = starts[i]; e1 = starts[i + 1]; }

    // ---- layer 1: aggregate x (3f, split list) + 3->16 transform, prescale ----
    if (act) {
        float ax = 0.f, ay = 0.f, az = 0.f;
        for (unsigned k = e0 + half; k < e1; k += 2) {
            const int s = csr8[k];
            const float4 v = *(const float4*)&arena[A_XS + s * 4];
            ax += v.x; ay += v.y; az += v.z;
        }
        if (!half) {                                    // self-loop once
            const float4 v = *(const float4*)&arena[A_XS + i * 4];
            ax += v.x; ay += v.y; az += v.z;
        }
        ax += __shfl_xor(ax, 1);
        ay += __shfl_xor(ay, 1);
        az += __shfl_xor(az, 1);
        ax *= di; ay *= di; az *= di;
        const int fb = half * 8;                        // this thread's 8 feats
        float h[8];
        #pragma unroll
        for (int f = 0; f < 8; ++f) {
            const float v = ax * w1s[fb + f] + ay * w1s[16 + fb + f]
                          + az * w1s[32 + fb + f];
            h[f] = fmaxf(v + b1s[fb + f], 0.f) * di;    // prescale for agg2
        }
        const int rot = (i >> 1) & 3;                   // slot rotation vs banks
        const int sl0 = (half * 2 + 0 + rot) & 3;
        const int sl1 = (half * 2 + 1 + rot) & 3;
        *(float4*)&arena[A_HS2 + i * 16 + sl0 * 4] = make_float4(h[0], h[1], h[2], h[3]);
        *(float4*)&arena[A_HS2 + i * 16 + sl1 * 4] = make_float4(h[4], h[5], h[6], h[7]);
    }
    __syncthreads();                                    // B5

    // ---- layer 2 aggregate: 16f gather into pair registers ----
    float4 c0 = {0,0,0,0}, c1 = {0,0,0,0}, c2 = {0,0,0,0}, c3 = {0,0,0,0};
    if (act) {
        for (unsigned k = e0 + half; k < e1; k += 2) {
            const int s = csr8[k];
            const float* p = &arena[A_HS2 + s * 16];
            const int rr = (s >> 1) & 3;
            const float4 v0 = *(const float4*)(p + (((0 + rr) & 3) << 2));
            const float4 v1 = *(const float4*)(p + (((1 + rr) & 3) << 2));
            const float4 v2 = *(const float4*)(p + (((2 + rr) & 3) << 2));
            const float4 v3 = *(const float4*)(p + (((3 + rr) & 3) << 2));
            c0.x += v0.x; c0.y += v0.y; c0.z += v0.z; c0.w += v0.w;
            c1.x += v1.x; c1.y += v1.y; c1.z += v1.z; c1.w += v1.w;
            c2.x += v2.x; c2.y += v2.y; c2.z += v2.z; c2.w += v2.w;
            c3.x += v3.x; c3.y += v3.y; c3.z += v3.z; c3.w += v3.w;
        }
        if (!half) {                                    // self-loop
            const float* p = &arena[A_HS2 + i * 16];
            const int rr = (i >> 1) & 3;
            const float4 v0 = *(const float4*)(p + (((0 + rr) & 3) << 2));
            const float4 v1 = *(const float4*)(p + (((1 + rr) & 3) << 2));
            const float4 v2 = *(const float4*)(p + (((2 + rr) & 3) << 2));
            const float4 v3 = *(const float4*)(p + (((3 + rr) & 3) << 2));
            c0.x += v0.x; c0.y += v0.y; c0.z += v0.z; c0.w += v0.w;
            c1.x += v1.x; c1.y += v1.y; c1.z += v1.z; c1.w += v1.w;
            c2.x += v2.x; c2.y += v2.y; c2.z += v2.z; c2.w += v2.w;
            c3.x += v3.x; c3.y += v3.y; c3.z += v3.z; c3.w += v3.w;
        }
        // pair merge: both threads end with all 16 sums
        c0.x += __shfl_xor(c0.x, 1); c0.y += __shfl_xor(c0.y, 1);
        c0.z += __shfl_xor(c0.z, 1); c0.w += __shfl_xor(c0.w, 1);
        c1.x += __shfl_xor(c1.x, 1); c1.y += __shfl_xor(c1.y, 1);
        c1.z += __shfl_xor(c1.z, 1); c1.w += __shfl_xor(c1.w, 1);
        c2.x += __shfl_xor(c2.x, 1); c2.y += __shfl_xor(c2.y, 1);
        c2.z += __shfl_xor(c2.z, 1); c2.w += __shfl_xor(c2.w, 1);
        c3.x += __shfl_xor(c3.x, 1); c3.y += __shfl_xor(c3.y, 1);
        c3.z += __shfl_xor(c3.z, 1); c3.w += __shfl_xor(c3.w, 1);
        c0.x *= di; c0.y *= di; c0.z *= di; c0.w *= di;
        c1.x *= di; c1.y *= di; c1.z *= di; c1.w *= di;
        c2.x *= di; c2.y *= di; c2.z *= di; c2.w *= di;
        c3.x *= di; c3.y *= di; c3.z *= di; c3.w *= di;
    }
    __syncthreads();                                    // B6 (all LDS reads done)

    // ---- 16->28 transform + relu -> H2 (overlays everything) ----
    if (act) {
        const float a2[16] = {c0.x, c0.y, c0.z, c0.w, c1.x, c1.y, c1.z, c1.w,
                              c2.x, c2.y, c2.z, c2.w, c3.x, c3.y, c3.z, c3.w};
        const int base = half * 14;                     // this thread's 14 feats
        float acc[14];
        #pragma unroll
        for (int j = 0; j < 14; ++j) acc[j] = b2s[base + j];
        #pragma unroll
        for (int k = 0; k < 16; ++k) {
            const float a = a2[k];
            const float* wr = &w2s[k * 28 + base];
            #pragma unroll
            for (int m = 0; m < 7; ++m) {               // 7x float2, 8B-aligned
                const float2 wv = *(const float2*)(wr + 2 * m);
                acc[2 * m]     = fmaf(a, wv.x, acc[2 * m]);
                acc[2 * m + 1] = fmaf(a, wv.y, acc[2 * m + 1]);
            }
        }
        float* hp = &arena[A_H2 + i * 28 + base];
        #pragma unroll
        for (int m = 0; m < 7; ++m) {
            const float2 hv = {fmaxf(acc[2 * m], 0.f), fmaxf(acc[2 * m + 1], 0.f)};
            *(float2*)(hp + 2 * m) = hv;
        }
    }
    __syncthreads();                                    // B7

    // ---- head: g = relu(h2_flat @ lw1 + lb1); out = g @ lw2 + lb2 ----
    float pj[16];
    #pragma unroll
    for (int j = 0; j < 16; ++j) pj[j] = 0.f;
    const float4* lw14 = (const float4*)lw1;
    for (int r = t; r < NPG * F2; r += 256) {
        const float hv = arena[A_H2 + r];
        const float4 aa = lw14[(long)r * 4 + 0];
        const float4 bb = lw14[(long)r * 4 + 1];
        const float4 cc = lw14[(long)r * 4 + 2];
        const float4 dd = lw14[(long)r * 4 + 3];
        pj[0]  = fmaf(hv, aa.x, pj[0]);  pj[1]  = fmaf(hv, aa.y, pj[1]);
        pj[2]  = fmaf(hv, aa.z, pj[2]);  pj[3]  = fmaf(hv, aa.w, pj[3]);
        pj[4]  = fmaf(hv, bb.x, pj[4]);  pj[5]  = fmaf(hv, bb.y, pj[5]);
        pj[6]  = fmaf(hv, bb.z, pj[6]);  pj[7]  = fmaf(hv, bb.w, pj[7]);
        pj[8]  = fmaf(hv, cc.x, pj[8]);  pj[9]  = fmaf(hv, cc.y, pj[9]);
        pj[10] = fmaf(hv, cc.z, pj[10]); pj[11] = fmaf(hv, cc.w, pj[11]);
        pj[12] = fmaf(hv, dd.x, pj[12]); pj[13] = fmaf(hv, dd.y, pj[13]);
        pj[14] = fmaf(hv, dd.z, pj[14]); pj[15] = fmaf(hv, dd.w, pj[15]);
    }
    #pragma unroll
    for (int j = 0; j < 16; ++j) {
        float v = pj[j];
        v += __shfl_xor(v, 1);
        v += __shfl_xor(v, 2);
        v += __shfl_xor(v, 4);
        v += __shfl_xor(v, 8);
        v += __shfl_xor(v, 16);
        v += __shfl_xor(v, 32);
        pj[j] = v;
    }
    if ((t & 63) == 0) {
        const int wid = t >> 6;
        #pragma unroll
        for (int j = 0; j < 16; ++j) wsum[wid * 16 + j] = pj[j];
    }
    __syncthreads();                                    // B8
    if (t < 16) {
        const float s = wsum[t] + wsum[16 + t] + wsum[32 + t] + wsum[48 + t];
        gsh[t] = fmaxf(s + lb1s[t], 0.f);
    }
    __syncthreads();                                    // B9
    if (t < 2) {
        float o = lb2s[t];
        #pragma unroll
        for (int j = 0; j < 16; ++j) o = fmaf(gsh[j], lw2s[j * 2 + t], o);
        out[g * 2 + t] = o;
    }
}

extern "C" void kernel_launch(void* const* d_in, const int* in_sizes, int n_in,
                              void* d_out, int out_size, void* d_ws, size_t ws_size,
                              hipStream_t stream) {
    const float* x   = (const float*)d_in[0];
    const int*   ei  = (const int*)d_in[1];
    const float* W1  = (const float*)d_in[2];
    const float* b1  = (const float*)d_in[3];
    const float* W2  = (const float*)d_in[4];
    const float* b2  = (const float*)d_in[5];
    const float* lw1 = (const float*)d_in[6];
    const float* lb1 = (const float*)d_in[7];
    const float* lw2 = (const float*)d_in[8];
    const float* lb2 = (const float*)d_in[9];
    float* out = (float*)d_out;

    gcn_fused<<<NGRAPH, 256, 0, stream>>>(x, ei, W1, b1, W2, b2,
                                          lw1, lb1, lw2, lb2, out);
}